// Round 2
// baseline (1194.479 us; speedup 1.0000x reference)
//
#include <hip/hip_runtime.h>
#include <hip/hip_bf16.h>
#include <cstdint>

// Encoder_Decoder: C=80 classes, H=128, N=sum(lengths)=20640, L_max=416.
// Phases:
//  1) concat extras into allf[:,128:224]
//  2) feat = relu(acbf @ appear_W^T + ab) -> allf[:, :128]   (GEMM K=1024)
//  3) dec  = relu(allf @ feat_W^T + fb)                      (GEMM K=224)
//  4) xp[d][start+t][g] = dec[gathered row] @ Wih[c,d]^T + bih   (per-class GEMM K=128)
//  5) GRU scan per (class, dir): 160 blocks x 128 threads, 3 rows/thread
//  6) out[n] = sigmoid(dot(outY[n,:256], out_W) + out_b)

// ---------------- 1. concat extras ----------------
__global__ __launch_bounds__(256) void concat_kernel(
    const float* __restrict__ score, const float* __restrict__ box,
    const float* __restrict__ orig, float* __restrict__ allf, int N)
{
    int idx = blockIdx.x * 256 + threadIdx.x;
    int total = N * 96;
    if (idx >= total) return;
    int n = idx / 96, j = idx - n * 96;
    float v;
    if (j < 32)      v = score[(size_t)n * 32 + j];
    else if (j < 64) v = box  [(size_t)n * 32 + j - 32];
    else             v = orig [(size_t)n * 32 + j - 64];
    allf[(size_t)n * 224 + 128 + j] = v;
}

// ---------------- generic fp32 GEMM: C(N x 128) = act(A(N x K) * B(128 x K)^T + bias) ----------------
// block: 256 thr, 64 rows x 128 cols, 4x8 micro-tile per thread, BK=16,
// register double-buffer: next tile's global loads issued before compute.
__global__ __launch_bounds__(256) void gemm128_kernel(
    const float* __restrict__ A, int lda,
    const float* __restrict__ B,            // 128 x K row-major
    const float* __restrict__ bias,
    float* __restrict__ Cc, int ldc,
    int N, int K, int do_relu)
{
    __shared__ __align__(16) float As[16][64];
    __shared__ __align__(16) float Bs[16][128];
    const int tid = threadIdx.x;
    const int tx = tid & 15, ty = tid >> 4;
    const int n0 = blockIdx.x * 64;
    const int arow = tid >> 2;

    float acc[4][8] = {};

    int ar = n0 + arow; if (ar > N - 1) ar = N - 1;
    const float* Aptr  = A + (size_t)ar * lda + (tid & 3) * 4;
    const int m0 = tid >> 2;                 // 0..63
    const int kq4 = (tid & 3) * 4;
    const float* Bptr0 = B + (size_t)m0 * K + (tid & 3) * 4;
    const float* Bptr1 = Bptr0 + (size_t)64 * K;

    float4 av = *(const float4*)(Aptr);
    float4 b0 = *(const float4*)(Bptr0);
    float4 b1 = *(const float4*)(Bptr1);

    for (int kb = 0; kb < K; kb += 16) {
        __syncthreads();   // finish previous compute before overwriting LDS
        As[kq4 + 0][arow] = av.x;
        As[kq4 + 1][arow] = av.y;
        As[kq4 + 2][arow] = av.z;
        As[kq4 + 3][arow] = av.w;
        Bs[kq4 + 0][m0] = b0.x; Bs[kq4 + 1][m0] = b0.y;
        Bs[kq4 + 2][m0] = b0.z; Bs[kq4 + 3][m0] = b0.w;
        Bs[kq4 + 0][m0 + 64] = b1.x; Bs[kq4 + 1][m0 + 64] = b1.y;
        Bs[kq4 + 2][m0 + 64] = b1.z; Bs[kq4 + 3][m0 + 64] = b1.w;
        __syncthreads();
        if (kb + 16 < K) {     // prefetch next tile; latency hidden under compute
            av = *(const float4*)(Aptr + kb + 16);
            b0 = *(const float4*)(Bptr0 + kb + 16);
            b1 = *(const float4*)(Bptr1 + kb + 16);
        }
        #pragma unroll
        for (int kk = 0; kk < 16; kk++) {
            float4 a = *(const float4*)&As[kk][ty * 4];
            float4 p = *(const float4*)&Bs[kk][tx * 8];
            float4 q = *(const float4*)&Bs[kk][tx * 8 + 4];
            float av4[4] = {a.x, a.y, a.z, a.w};
            float bv[8]  = {p.x, p.y, p.z, p.w, q.x, q.y, q.z, q.w};
            #pragma unroll
            for (int i = 0; i < 4; i++)
                #pragma unroll
                for (int j = 0; j < 8; j++)
                    acc[i][j] = fmaf(av4[i], bv[j], acc[i][j]);
        }
    }

    #pragma unroll
    for (int i = 0; i < 4; i++) {
        int row = n0 + ty * 4 + i;
        if (row >= N) continue;
        float o[8];
        #pragma unroll
        for (int j = 0; j < 8; j++) {
            float v = acc[i][j] + bias[tx * 8 + j];
            if (do_relu) v = v > 0.f ? v : 0.f;
            o[j] = v;
        }
        float4* dst = (float4*)(Cc + (size_t)row * ldc + tx * 8);
        dst[0] = make_float4(o[0], o[1], o[2], o[3]);
        dst[1] = make_float4(o[4], o[5], o[6], o[7]);
    }
}

// ---------------- 4. Xp per-class GEMM (K=128) with direction-dependent row gather ----------------
__global__ __launch_bounds__(256) void xp_kernel(
    const float* __restrict__ dec,    // N x 128
    const float* __restrict__ Wih,    // C x 2 x 384 x 128
    const float* __restrict__ bih,    // C x 2 x 384
    const int* __restrict__ ucl,      // C+1
    float* __restrict__ xp,           // 2 x N x 384
    int N)
{
    const int c = blockIdx.x;
    const int tile = blockIdx.y;
    const int d  = blockIdx.z / 3;
    const int mt = blockIdx.z % 3;
    const int start = ucl[c];
    const int len = ucl[c + 1] - start;
    const int t0 = tile * 64;
    if (t0 >= len) return;

    __shared__ __align__(16) float As[16][64];
    __shared__ __align__(16) float Bs[16][128];
    const int tid = threadIdx.x;
    const int tx = tid & 15, ty = tid >> 4;
    const int arow = tid >> 2;

    int t = t0 + arow; if (t > len - 1) t = len - 1;
    int srow = start + (d ? (len - 1 - t) : t);
    const float* Aptr = dec + (size_t)srow * 128 + (tid & 3) * 4;

    const float* Bbase = Wih + ((size_t)(c * 2 + d) * 384 + mt * 128) * 128;
    const int m0 = tid >> 2;
    const int kq4 = (tid & 3) * 4;
    const float* Bptr0 = Bbase + (size_t)m0 * 128 + (tid & 3) * 4;
    const float* Bptr1 = Bptr0 + (size_t)64 * 128;

    float4 av = *(const float4*)(Aptr);
    float4 b0 = *(const float4*)(Bptr0);
    float4 b1 = *(const float4*)(Bptr1);

    float acc[4][8] = {};
    for (int kb = 0; kb < 128; kb += 16) {
        __syncthreads();
        As[kq4 + 0][arow] = av.x;
        As[kq4 + 1][arow] = av.y;
        As[kq4 + 2][arow] = av.z;
        As[kq4 + 3][arow] = av.w;
        Bs[kq4 + 0][m0] = b0.x; Bs[kq4 + 1][m0] = b0.y;
        Bs[kq4 + 2][m0] = b0.z; Bs[kq4 + 3][m0] = b0.w;
        Bs[kq4 + 0][m0 + 64] = b1.x; Bs[kq4 + 1][m0 + 64] = b1.y;
        Bs[kq4 + 2][m0 + 64] = b1.z; Bs[kq4 + 3][m0 + 64] = b1.w;
        __syncthreads();
        if (kb + 16 < 128) {
            av = *(const float4*)(Aptr + kb + 16);
            b0 = *(const float4*)(Bptr0 + kb + 16);
            b1 = *(const float4*)(Bptr1 + kb + 16);
        }
        #pragma unroll
        for (int kk = 0; kk < 16; kk++) {
            float4 a = *(const float4*)&As[kk][ty * 4];
            float4 p = *(const float4*)&Bs[kk][tx * 8];
            float4 q = *(const float4*)&Bs[kk][tx * 8 + 4];
            float av4[4] = {a.x, a.y, a.z, a.w};
            float bv[8]  = {p.x, p.y, p.z, p.w, q.x, q.y, q.z, q.w};
            #pragma unroll
            for (int i = 0; i < 4; i++)
                #pragma unroll
                for (int j = 0; j < 8; j++)
                    acc[i][j] = fmaf(av4[i], bv[j], acc[i][j]);
        }
    }

    const float* bias = bih + (size_t)(c * 2 + d) * 384 + mt * 128;
    #pragma unroll
    for (int i = 0; i < 4; i++) {
        int tt = t0 + ty * 4 + i;
        if (tt >= len) continue;
        float o[8];
        #pragma unroll
        for (int j = 0; j < 8; j++) o[j] = acc[i][j] + bias[tx * 8 + j];
        float4* dst = (float4*)(xp + ((size_t)d * N + start + tt) * 384 + mt * 128 + tx * 8);
        dst[0] = make_float4(o[0], o[1], o[2], o[3]);
        dst[1] = make_float4(o[4], o[5], o[6], o[7]);
    }
}

// ---------------- 5. GRU scan: one block per (class, dir), 128 threads, 3 rows/thread ----------------
// Thread g owns gate rows {g, g+128, g+256} => gate combine for h[g] is thread-local.
// h double-buffered in LDS => ONE barrier per step. w rows live in ~384 VGPRs
// (launch_bounds(128,1) allows up to 512 VGPR/wave, 2 waves/CU is all we need
// since only 160 blocks exist).
__global__ __launch_bounds__(128, 1) void gru_kernel(
    const float* __restrict__ xp,     // 2 x N x 384
    const float* __restrict__ Whh,    // C x 2 x 384 x 128
    const float* __restrict__ bhh,    // C x 2 x 384
    const int* __restrict__ ucl,
    float* __restrict__ outY,         // N x 256
    int N)
{
    const int c = blockIdx.x, d = blockIdx.y;
    const int start = ucl[c];
    const int len = ucl[c + 1] - start;
    const int g = threadIdx.x;        // 0..127

    const float* wbase = Whh + (size_t)(c * 2 + d) * 384 * 128;
    float4 w0[32], w1[32], w2[32];
    {
        const float4* r0 = (const float4*)(wbase + (size_t)g * 128);
        const float4* r1 = (const float4*)(wbase + (size_t)(g + 128) * 128);
        const float4* r2 = (const float4*)(wbase + (size_t)(g + 256) * 128);
        #pragma unroll
        for (int i = 0; i < 32; i++) w0[i] = r0[i];
        #pragma unroll
        for (int i = 0; i < 32; i++) w1[i] = r1[i];
        #pragma unroll
        for (int i = 0; i < 32; i++) w2[i] = r2[i];
    }
    const float* bb = bhh + (size_t)(c * 2 + d) * 384;
    const float bh0 = bb[g], bh1 = bb[g + 128], bh2 = bb[g + 256];

    __shared__ __align__(16) float hbuf[2][128];
    hbuf[0][g] = 0.f;
    const float* xpb = xp + ((size_t)d * N + start) * 384;
    float* outb = outY + (size_t)start * 256 + d * 128;

    // prefetch x(0)
    float x0 = xpb[g], x1 = xpb[g + 128], x2 = xpb[g + 256];
    float hcur = 0.f;
    __syncthreads();

    for (int t = 0; t < len; t++) {
        const float* __restrict__ hb = hbuf[t & 1];
        float* __restrict__ hn = hbuf[(t & 1) ^ 1];
        // prefetch x(t+1) — latency hidden under the matvec
        float nx0 = 0.f, nx1 = 0.f, nx2 = 0.f;
        if (t + 1 < len) {
            const float* xr = xpb + (size_t)(t + 1) * 384;
            nx0 = xr[g]; nx1 = xr[g + 128]; nx2 = xr[g + 256];
        }
        // three 128-dots against shared h (broadcast LDS reads, 12 FMA per b128 read)
        float a0 = bh0, a1 = bh1, a2 = bh2;
        #pragma unroll
        for (int i = 0; i < 32; i++) {
            float4 hv = ((const float4*)hb)[i];
            a0 = fmaf(w0[i].x, hv.x, a0);
            a1 = fmaf(w1[i].x, hv.x, a1);
            a2 = fmaf(w2[i].x, hv.x, a2);
            a0 = fmaf(w0[i].y, hv.y, a0);
            a1 = fmaf(w1[i].y, hv.y, a1);
            a2 = fmaf(w2[i].y, hv.y, a2);
            a0 = fmaf(w0[i].z, hv.z, a0);
            a1 = fmaf(w1[i].z, hv.z, a1);
            a2 = fmaf(w2[i].z, hv.z, a2);
            a0 = fmaf(w0[i].w, hv.w, a0);
            a1 = fmaf(w1[i].w, hv.w, a1);
            a2 = fmaf(w2[i].w, hv.w, a2);
        }
        float r = 1.f / (1.f + __expf(-(x0 + a0)));
        float z = 1.f / (1.f + __expf(-(x1 + a1)));
        float pre = x2 + r * a2;
        // tanh via exp: tanh(x) = 1 - 2/(exp(2x)+1)
        float n = 1.f - 2.f / (__expf(2.f * pre) + 1.f);
        float hnew = (1.f - z) * n + z * hcur;
        hn[g] = hnew;
        hcur = hnew;
        int tt = d ? (len - 1 - t) : t;
        outb[(size_t)tt * 256 + g] = hnew;
        x0 = nx0; x1 = nx1; x2 = nx2;
        __syncthreads();   // single barrier: separates hn writes from next step's reads
    }
}

// ---------------- 6. head: sigmoid(dot(outY[n], out_W) + b) ----------------
__global__ __launch_bounds__(256) void final_kernel(
    const float* __restrict__ outY,   // N x 256
    const float* __restrict__ outW,   // 256
    const float* __restrict__ outb,   // 1
    float* __restrict__ out, int N)
{
    __shared__ __align__(16) float wsh[256];
    wsh[threadIdx.x] = outW[threadIdx.x];
    __syncthreads();
    const int lane = threadIdx.x & 63;
    const int wave = (blockIdx.x * 256 + threadIdx.x) >> 6;
    const int nw = gridDim.x * 4;
    float4 w4 = *(const float4*)&wsh[lane * 4];
    float b = outb[0];
    for (int n = wave; n < N; n += nw) {
        float4 y = *(const float4*)(outY + (size_t)n * 256 + lane * 4);
        float p = y.x * w4.x + y.y * w4.y + y.z * w4.z + y.w * w4.w;
        #pragma unroll
        for (int off = 32; off > 0; off >>= 1) p += __shfl_down(p, off);
        if (lane == 0) out[n] = 1.f / (1.f + __expf(-(p + b)));
    }
}

extern "C" void kernel_launch(void* const* d_in, const int* in_sizes, int n_in,
                              void* d_out, int out_size, void* d_ws, size_t ws_size,
                              hipStream_t stream)
{
    const float* acbf  = (const float*)d_in[3];
    const float* score = (const float*)d_in[4];
    const float* box   = (const float*)d_in[5];
    const float* orig  = (const float*)d_in[6];
    const int*   ucl   = (const int*)d_in[8];
    const float* aW  = (const float*)d_in[9];
    const float* ab  = (const float*)d_in[10];
    const float* fW  = (const float*)d_in[11];
    const float* fb  = (const float*)d_in[12];
    const float* Wih = (const float*)d_in[13];
    const float* Whh = (const float*)d_in[14];
    const float* bih = (const float*)d_in[15];
    const float* bhh = (const float*)d_in[16];
    const float* oW  = (const float*)d_in[17];
    const float* ob  = (const float*)d_in[18];
    float* out = (float*)d_out;

    const int N = in_sizes[3] / 1024;   // 20640
    const int C = in_sizes[7];          // 80

    // workspace layout (floats): allf N*224 | dec N*128 | xp 2*N*384  (~92.5 MB)
    // outY (N*256) overlaps allf+dec head — both dead once the GRU starts.
    float* ws   = (float*)d_ws;
    float* allf = ws;
    float* dec  = ws + (size_t)N * 224;
    float* xp   = dec + (size_t)N * 128;
    float* outY = ws;

    dim3 blk(256);
    concat_kernel<<<dim3((N * 96 + 255) / 256), blk, 0, stream>>>(score, box, orig, allf, N);
    gemm128_kernel<<<dim3((N + 63) / 64), blk, 0, stream>>>(acbf, 1024, aW, ab, allf, 224, N, 1024, 1);
    gemm128_kernel<<<dim3((N + 63) / 64), blk, 0, stream>>>(allf, 224, fW, fb, dec, 128, N, 224, 1);
    xp_kernel<<<dim3(C, 7, 6), blk, 0, stream>>>(dec, Wih, bih, ucl, xp, N);
    gru_kernel<<<dim3(C, 2), dim3(128), 0, stream>>>(xp, Whh, bhh, ucl, outY, N);
    final_kernel<<<dim3(160), blk, 0, stream>>>(outY, oW, ob, out, N);
}

// Round 3
// 715.603 us; speedup vs baseline: 1.6692x; 1.6692x over previous
//
#include <hip/hip_runtime.h>
#include <hip/hip_bf16.h>
#include <cstdint>

// Encoder_Decoder: C=80 classes, H=128, N=sum(lengths)=20640, L_max=416.
// Phases:
//  1) concat extras into allf[:,128:224]
//  2) feat = relu(acbf @ appear_W^T + ab) -> allf[:, :128]   (GEMM K=1024)
//  3) dec  = relu(allf @ feat_W^T + fb)                      (GEMM K=224)
//  4) xp[d][start+t][g] = dec[gathered row] @ Wih[c,d]^T + bih   (per-class GEMM K=128)
//  5) GRU scan per (class, dir): 128 thr x 3 rows, f16 weights in VGPRs + v_dot2
//  6) out[n] = sigmoid(dot(outY[n,:256], out_W) + out_b)

typedef _Float16 half2_t __attribute__((ext_vector_type(2)));
typedef _Float16 half8_t __attribute__((ext_vector_type(8)));

// ---------------- 1. concat extras ----------------
__global__ __launch_bounds__(256) void concat_kernel(
    const float* __restrict__ score, const float* __restrict__ box,
    const float* __restrict__ orig, float* __restrict__ allf, int N)
{
    int idx = blockIdx.x * 256 + threadIdx.x;
    int total = N * 96;
    if (idx >= total) return;
    int n = idx / 96, j = idx - n * 96;
    float v;
    if (j < 32)      v = score[(size_t)n * 32 + j];
    else if (j < 64) v = box  [(size_t)n * 32 + j - 32];
    else             v = orig [(size_t)n * 32 + j - 64];
    allf[(size_t)n * 224 + 128 + j] = v;
}

// ---------------- generic fp32 GEMM: C(N x 128) = act(A(N x K) * B(128 x K)^T + bias) ----------------
__global__ __launch_bounds__(256) void gemm128_kernel(
    const float* __restrict__ A, int lda,
    const float* __restrict__ B,            // 128 x K row-major
    const float* __restrict__ bias,
    float* __restrict__ Cc, int ldc,
    int N, int K, int do_relu)
{
    __shared__ __align__(16) float As[16][64];
    __shared__ __align__(16) float Bs[16][128];
    const int tid = threadIdx.x;
    const int tx = tid & 15, ty = tid >> 4;
    const int n0 = blockIdx.x * 64;
    const int arow = tid >> 2;

    float acc[4][8] = {};

    int ar = n0 + arow; if (ar > N - 1) ar = N - 1;
    const float* Aptr  = A + (size_t)ar * lda + (tid & 3) * 4;
    const int m0 = tid >> 2;                 // 0..63
    const int kq4 = (tid & 3) * 4;
    const float* Bptr0 = B + (size_t)m0 * K + (tid & 3) * 4;
    const float* Bptr1 = Bptr0 + (size_t)64 * K;

    float4 av = *(const float4*)(Aptr);
    float4 b0 = *(const float4*)(Bptr0);
    float4 b1 = *(const float4*)(Bptr1);

    for (int kb = 0; kb < K; kb += 16) {
        __syncthreads();   // finish previous compute before overwriting LDS
        As[kq4 + 0][arow] = av.x;
        As[kq4 + 1][arow] = av.y;
        As[kq4 + 2][arow] = av.z;
        As[kq4 + 3][arow] = av.w;
        Bs[kq4 + 0][m0] = b0.x; Bs[kq4 + 1][m0] = b0.y;
        Bs[kq4 + 2][m0] = b0.z; Bs[kq4 + 3][m0] = b0.w;
        Bs[kq4 + 0][m0 + 64] = b1.x; Bs[kq4 + 1][m0 + 64] = b1.y;
        Bs[kq4 + 2][m0 + 64] = b1.z; Bs[kq4 + 3][m0 + 64] = b1.w;
        __syncthreads();
        if (kb + 16 < K) {     // prefetch next tile; latency hidden under compute
            av = *(const float4*)(Aptr + kb + 16);
            b0 = *(const float4*)(Bptr0 + kb + 16);
            b1 = *(const float4*)(Bptr1 + kb + 16);
        }
        #pragma unroll
        for (int kk = 0; kk < 16; kk++) {
            float4 a = *(const float4*)&As[kk][ty * 4];
            float4 p = *(const float4*)&Bs[kk][tx * 8];
            float4 q = *(const float4*)&Bs[kk][tx * 8 + 4];
            float av4[4] = {a.x, a.y, a.z, a.w};
            float bv[8]  = {p.x, p.y, p.z, p.w, q.x, q.y, q.z, q.w};
            #pragma unroll
            for (int i = 0; i < 4; i++)
                #pragma unroll
                for (int j = 0; j < 8; j++)
                    acc[i][j] = fmaf(av4[i], bv[j], acc[i][j]);
        }
    }

    #pragma unroll
    for (int i = 0; i < 4; i++) {
        int row = n0 + ty * 4 + i;
        if (row >= N) continue;
        float o[8];
        #pragma unroll
        for (int j = 0; j < 8; j++) {
            float v = acc[i][j] + bias[tx * 8 + j];
            if (do_relu) v = v > 0.f ? v : 0.f;
            o[j] = v;
        }
        float4* dst = (float4*)(Cc + (size_t)row * ldc + tx * 8);
        dst[0] = make_float4(o[0], o[1], o[2], o[3]);
        dst[1] = make_float4(o[4], o[5], o[6], o[7]);
    }
}

// ---------------- 4. Xp per-class GEMM (K=128) with direction-dependent row gather ----------------
__global__ __launch_bounds__(256) void xp_kernel(
    const float* __restrict__ dec,    // N x 128
    const float* __restrict__ Wih,    // C x 2 x 384 x 128
    const float* __restrict__ bih,    // C x 2 x 384
    const int* __restrict__ ucl,      // C+1
    float* __restrict__ xp,           // 2 x N x 384
    int N)
{
    const int c = blockIdx.x;
    const int tile = blockIdx.y;
    const int d  = blockIdx.z / 3;
    const int mt = blockIdx.z % 3;
    const int start = ucl[c];
    const int len = ucl[c + 1] - start;
    const int t0 = tile * 64;
    if (t0 >= len) return;

    __shared__ __align__(16) float As[16][64];
    __shared__ __align__(16) float Bs[16][128];
    const int tid = threadIdx.x;
    const int tx = tid & 15, ty = tid >> 4;
    const int arow = tid >> 2;

    int t = t0 + arow; if (t > len - 1) t = len - 1;
    int srow = start + (d ? (len - 1 - t) : t);
    const float* Aptr = dec + (size_t)srow * 128 + (tid & 3) * 4;

    const float* Bbase = Wih + ((size_t)(c * 2 + d) * 384 + mt * 128) * 128;
    const int m0 = tid >> 2;
    const int kq4 = (tid & 3) * 4;
    const float* Bptr0 = Bbase + (size_t)m0 * 128 + (tid & 3) * 4;
    const float* Bptr1 = Bptr0 + (size_t)64 * 128;

    float4 av = *(const float4*)(Aptr);
    float4 b0 = *(const float4*)(Bptr0);
    float4 b1 = *(const float4*)(Bptr1);

    float acc[4][8] = {};
    for (int kb = 0; kb < 128; kb += 16) {
        __syncthreads();
        As[kq4 + 0][arow] = av.x;
        As[kq4 + 1][arow] = av.y;
        As[kq4 + 2][arow] = av.z;
        As[kq4 + 3][arow] = av.w;
        Bs[kq4 + 0][m0] = b0.x; Bs[kq4 + 1][m0] = b0.y;
        Bs[kq4 + 2][m0] = b0.z; Bs[kq4 + 3][m0] = b0.w;
        Bs[kq4 + 0][m0 + 64] = b1.x; Bs[kq4 + 1][m0 + 64] = b1.y;
        Bs[kq4 + 2][m0 + 64] = b1.z; Bs[kq4 + 3][m0 + 64] = b1.w;
        __syncthreads();
        if (kb + 16 < 128) {
            av = *(const float4*)(Aptr + kb + 16);
            b0 = *(const float4*)(Bptr0 + kb + 16);
            b1 = *(const float4*)(Bptr1 + kb + 16);
        }
        #pragma unroll
        for (int kk = 0; kk < 16; kk++) {
            float4 a = *(const float4*)&As[kk][ty * 4];
            float4 p = *(const float4*)&Bs[kk][tx * 8];
            float4 q = *(const float4*)&Bs[kk][tx * 8 + 4];
            float av4[4] = {a.x, a.y, a.z, a.w};
            float bv[8]  = {p.x, p.y, p.z, p.w, q.x, q.y, q.z, q.w};
            #pragma unroll
            for (int i = 0; i < 4; i++)
                #pragma unroll
                for (int j = 0; j < 8; j++)
                    acc[i][j] = fmaf(av4[i], bv[j], acc[i][j]);
        }
    }

    const float* bias = bih + (size_t)(c * 2 + d) * 384 + mt * 128;
    #pragma unroll
    for (int i = 0; i < 4; i++) {
        int tt = t0 + ty * 4 + i;
        if (tt >= len) continue;
        float o[8];
        #pragma unroll
        for (int j = 0; j < 8; j++) o[j] = acc[i][j] + bias[tx * 8 + j];
        float4* dst = (float4*)(xp + ((size_t)d * N + start + tt) * 384 + mt * 128 + tx * 8);
        dst[0] = make_float4(o[0], o[1], o[2], o[3]);
        dst[1] = make_float4(o[4], o[5], o[6], o[7]);
    }
}

// ---------------- 5. GRU scan ----------------
// One block per (class,dir), 128 threads. Thread g owns gate rows {g, g+128, g+256}.
// Whh rows live in VGPRs as packed f16 (3*64 = 192 VGPRs — fits under the 256 arch
// VGPR cap, unlike fp32 which spilled to scratch in R2). Matvec via v_dot2_f32_f16
// (2 MAC/inst, fp32 accumulate). h broadcast through LDS as f16 (8 ds_read_b128
// per thread per step). Carried state hcur stays fp32 in-thread. One barrier/step.
__global__ __launch_bounds__(128, 1) void gru_kernel(
    const float* __restrict__ xp,     // 2 x N x 384
    const float* __restrict__ Whh,    // C x 2 x 384 x 128
    const float* __restrict__ bhh,    // C x 2 x 384
    const int* __restrict__ ucl,
    float* __restrict__ outY,         // N x 256
    int N)
{
    const int c = blockIdx.x, d = blockIdx.y;
    const int start = ucl[c];
    const int len = ucl[c + 1] - start;
    const int g = threadIdx.x;        // 0..127

    const float* wbase = Whh + (size_t)(c * 2 + d) * 384 * 128;
    half2_t w0[64], w1[64], w2[64];
    {
        const float2* r0 = (const float2*)(wbase + (size_t)g * 128);
        const float2* r1 = (const float2*)(wbase + (size_t)(g + 128) * 128);
        const float2* r2 = (const float2*)(wbase + (size_t)(g + 256) * 128);
        #pragma unroll
        for (int i = 0; i < 64; i++) {
            float2 a = r0[i];
            w0[i] = half2_t{(_Float16)a.x, (_Float16)a.y};
        }
        #pragma unroll
        for (int i = 0; i < 64; i++) {
            float2 a = r1[i];
            w1[i] = half2_t{(_Float16)a.x, (_Float16)a.y};
        }
        #pragma unroll
        for (int i = 0; i < 64; i++) {
            float2 a = r2[i];
            w2[i] = half2_t{(_Float16)a.x, (_Float16)a.y};
        }
    }
    const float* bb = bhh + (size_t)(c * 2 + d) * 384;
    const float bh0 = bb[g], bh1 = bb[g + 128], bh2 = bb[g + 256];

    // h as f16: 64 half2 (256 B) per buffer, double-buffered
    __shared__ __align__(16) half2_t hbuf[2][64];
    if (g < 64) { hbuf[0][g] = half2_t{(_Float16)0.f, (_Float16)0.f}; }
    const float* xpb = xp + ((size_t)d * N + start) * 384;
    float* outb = outY + (size_t)start * 256 + d * 128;

    float x0 = xpb[g], x1 = xpb[g + 128], x2 = xpb[g + 256];
    float hcur = 0.f;
    __syncthreads();

    for (int t = 0; t < len; t++) {
        const half8_t* __restrict__ hp = (const half8_t*)hbuf[t & 1];
        _Float16* __restrict__ hn = (_Float16*)hbuf[(t & 1) ^ 1];
        // prefetch x(t+1) — latency hidden under the matvec
        float nx0 = 0.f, nx1 = 0.f, nx2 = 0.f;
        if (t + 1 < len) {
            const float* xr = xpb + (size_t)(t + 1) * 384;
            nx0 = xr[g]; nx1 = xr[g + 128]; nx2 = xr[g + 256];
        }
        // three 128-dots vs shared h: 16 b128 LDS reads, 192 v_dot2 per thread
        float a0 = bh0, a1 = bh1, a2 = bh2;
        #pragma unroll
        for (int i = 0; i < 16; i++) {
            union { half8_t v; half2_t h2[4]; } u;
            u.v = hp[i];
            #pragma unroll
            for (int j = 0; j < 4; j++) {
                a0 = __builtin_amdgcn_fdot2(w0[i * 4 + j], u.h2[j], a0, false);
                a1 = __builtin_amdgcn_fdot2(w1[i * 4 + j], u.h2[j], a1, false);
                a2 = __builtin_amdgcn_fdot2(w2[i * 4 + j], u.h2[j], a2, false);
            }
        }
        float r = 1.f / (1.f + __expf(-(x0 + a0)));
        float z = 1.f / (1.f + __expf(-(x1 + a1)));
        float pre = x2 + r * a2;
        float n = 1.f - 2.f / (__expf(2.f * pre) + 1.f);   // tanh
        float hnew = (1.f - z) * n + z * hcur;
        hn[g] = (_Float16)hnew;       // f16 broadcast copy for next step's matvec
        hcur = hnew;                  // carried state stays fp32
        int tt = d ? (len - 1 - t) : t;
        outb[(size_t)tt * 256 + g] = hnew;
        x0 = nx0; x1 = nx1; x2 = nx2;
        __syncthreads();   // single barrier: hn writes vs next step's reads
    }
}

// ---------------- 6. head: sigmoid(dot(outY[n], out_W) + b) ----------------
__global__ __launch_bounds__(256) void final_kernel(
    const float* __restrict__ outY,   // N x 256
    const float* __restrict__ outW,   // 256
    const float* __restrict__ outb,   // 1
    float* __restrict__ out, int N)
{
    __shared__ __align__(16) float wsh[256];
    wsh[threadIdx.x] = outW[threadIdx.x];
    __syncthreads();
    const int lane = threadIdx.x & 63;
    const int wave = (blockIdx.x * 256 + threadIdx.x) >> 6;
    const int nw = gridDim.x * 4;
    float4 w4 = *(const float4*)&wsh[lane * 4];
    float b = outb[0];
    for (int n = wave; n < N; n += nw) {
        float4 y = *(const float4*)(outY + (size_t)n * 256 + lane * 4);
        float p = y.x * w4.x + y.y * w4.y + y.z * w4.z + y.w * w4.w;
        #pragma unroll
        for (int off = 32; off > 0; off >>= 1) p += __shfl_down(p, off);
        if (lane == 0) out[n] = 1.f / (1.f + __expf(-(p + b)));
    }
}

extern "C" void kernel_launch(void* const* d_in, const int* in_sizes, int n_in,
                              void* d_out, int out_size, void* d_ws, size_t ws_size,
                              hipStream_t stream)
{
    const float* acbf  = (const float*)d_in[3];
    const float* score = (const float*)d_in[4];
    const float* box   = (const float*)d_in[5];
    const float* orig  = (const float*)d_in[6];
    const int*   ucl   = (const int*)d_in[8];
    const float* aW  = (const float*)d_in[9];
    const float* ab  = (const float*)d_in[10];
    const float* fW  = (const float*)d_in[11];
    const float* fb  = (const float*)d_in[12];
    const float* Wih = (const float*)d_in[13];
    const float* Whh = (const float*)d_in[14];
    const float* bih = (const float*)d_in[15];
    const float* bhh = (const float*)d_in[16];
    const float* oW  = (const float*)d_in[17];
    const float* ob  = (const float*)d_in[18];
    float* out = (float*)d_out;

    const int N = in_sizes[3] / 1024;   // 20640
    const int C = in_sizes[7];          // 80

    // workspace layout (floats): allf N*224 | dec N*128 | xp 2*N*384  (~92.5 MB)
    // outY (N*256) overlaps allf+dec head — both dead once the GRU starts.
    float* ws   = (float*)d_ws;
    float* allf = ws;
    float* dec  = ws + (size_t)N * 224;
    float* xp   = dec + (size_t)N * 128;
    float* outY = ws;

    dim3 blk(256);
    concat_kernel<<<dim3((N * 96 + 255) / 256), blk, 0, stream>>>(score, box, orig, allf, N);
    gemm128_kernel<<<dim3((N + 63) / 64), blk, 0, stream>>>(acbf, 1024, aW, ab, allf, 224, N, 1024, 1);
    gemm128_kernel<<<dim3((N + 63) / 64), blk, 0, stream>>>(allf, 224, fW, fb, dec, 128, N, 224, 1);
    xp_kernel<<<dim3(C, 7, 6), blk, 0, stream>>>(dec, Wih, bih, ucl, xp, N);
    gru_kernel<<<dim3(C, 2), dim3(128), 0, stream>>>(xp, Whh, bhh, ucl, outY, N);
    final_kernel<<<dim3(160), blk, 0, stream>>>(outY, oW, ob, out, N);
}